// Round 4
// baseline (479.356 us; speedup 1.0000x reference)
//
#include <hip/hip_runtime.h>
#include <hip/hip_bf16.h>

typedef __attribute__((ext_vector_type(8))) short bf16x8;
typedef __attribute__((ext_vector_type(4))) float f32x4;

__device__ inline ushort f2bf(float f) {
    uint u = __float_as_uint(f);
    u += 0x7fff + ((u >> 16) & 1);
    return (ushort)(u >> 16);
}
__device__ inline float bf2f(ushort h) {
    return __uint_as_float(((uint)h) << 16);
}

__device__ inline void gload16(const void* g, void* lds) {
    __builtin_amdgcn_global_load_lds(
        (const __attribute__((address_space(1))) void*)g,
        (__attribute__((address_space(3))) void*)lds, 16, 0, 0);
}

// ---------------- converts ----------------
__global__ void conv_bf16(const float* __restrict__ in, ushort* __restrict__ out, int n4) {
    int i = blockIdx.x * 256 + threadIdx.x;
    if (i >= n4) return;
    float4 a = ((const float4*)in)[i];
    ushort4 o;
    o.x = f2bf(a.x); o.y = f2bf(a.y); o.z = f2bf(a.z); o.w = f2bf(a.w);
    ((ushort4*)out)[i] = o;
}

// in: fp32 [K,N] -> out: bf16 [N,K]
__global__ void wconv_t(const float* __restrict__ in, ushort* __restrict__ out, int K, int N) {
    __shared__ float tile[32][33];
    int kb = blockIdx.y * 32, nb = blockIdx.x * 32;
    int tx = threadIdx.x & 31, ty = threadIdx.x >> 5;  // 32 x 8
#pragma unroll
    for (int i = 0; i < 4; i++)
        tile[ty + i * 8][tx] = in[(size_t)(kb + ty + i * 8) * N + nb + tx];
    __syncthreads();
#pragma unroll
    for (int i = 0; i < 4; i++) {
        int n = nb + ty + i * 8, k = kb + tx;
        out[(size_t)n * K + k] = f2bf(tile[tx][ty + i * 8]);
    }
}

__global__ void biascat(const float* __restrict__ a, const float* __restrict__ b,
                        const float* __restrict__ c, float* __restrict__ o) {
    int i = blockIdx.x * 256 + threadIdx.x;
    if (i < 512) o[i] = a[i];
    else if (i < 1024) o[i] = b[i - 512];
    else if (i < 1536) o[i] = c[i - 1024];
}

// ============ 256x256 deep-pipelined GEMM: C = A[M,K] @ Bt[N,K]^T + bias ============
// 512 threads (8 waves, 2Mx4N), BK=32, 4-buffer LDS rotation (128 KB dynamic),
// 3-deep prefetch with counted vmcnt (never 0 in main loop).
// LDS buffer kt&3: A at +0 (256 rows x 32 cols bf16, 64B/row), B at +16384.
// Swizzle: 16B chunk index ^= (row>>1)&3  (applied to gload SOURCE and ds_read addr;
// gload dest stays linear -- rule #21).
// EPI: 2 = relu bf16; 3 = bf16 residual add; 4 = fused QKV (seg<2: elu+1) -> [3][M][512]
template <int EPI>
__global__ __launch_bounds__(512, 2) void gemm256(
    const ushort* __restrict__ A, const ushort* __restrict__ Bt,
    const float* __restrict__ bias, const ushort* __restrict__ res16,
    ushort* __restrict__ out16, int M, int N, int K, int nbx) {
    extern __shared__ char smem[];  // 4 * 32768
    const int t = threadIdx.x;
    const int w = t >> 6, l = t & 63;
    const int wr = w >> 2, wc = w & 3;
    // XCD-chunked bijective swizzle (grid divisible by 8)
    const int nwg = gridDim.x;
    const int cpx = nwg >> 3;
    const int swz = (blockIdx.x & 7) * cpx + (blockIdx.x >> 3);
    const int bx = swz % nbx, by = swz / nbx;

    // staging source addresses: thread t covers storage bytes rd*8192 + t*16 of each tile.
    // storage row = t>>2 (+128 for rd1), storage chunk = t&3; source logical chunk = (t&3)^((t>>3)&3)
    const int sc = (t & 3) ^ ((t >> 3) & 3);
    const ushort* gA0 = A + (size_t)(by * 256 + (t >> 2)) * K + sc * 8;
    const ushort* gA1 = gA0 + (size_t)128 * K;
    const ushort* gB0 = Bt + (size_t)(bx * 256 + (t >> 2)) * K + sc * 8;
    const ushort* gB1 = gB0 + (size_t)128 * K;
    char* ldsW = smem + (w << 10);  // wave-uniform base within each 8KB round

#define STAGE(kt)                                             \
    {                                                         \
        char* Lb = smem + ((kt) & 3) * 32768 + (w << 10);     \
        const int ko_ = (kt) * 32;                            \
        gload16(gA0 + ko_, Lb);                               \
        gload16(gA1 + ko_, Lb + 8192);                        \
        gload16(gB0 + ko_, Lb + 16384);                       \
        gload16(gB1 + ko_, Lb + 24576);                       \
    }

    f32x4 acc[8][4] = {};
    const int Kt = K >> 5;

    // ds_read offsets (constant per thread): logical (row, kchunk=l>>4) -> swizzled chunk
    const int R0a = wr * 128 + (l & 15);
    const int offA = R0a * 64 + (((l >> 4) ^ ((R0a >> 1) & 3)) << 4);
    const int R0b = wc * 64 + (l & 15);
    const int offB = 16384 + R0b * 64 + (((l >> 4) ^ ((R0b >> 1) & 3)) << 4);

    // prologue: 3 K-tiles in flight
    STAGE(0); STAGE(1); STAGE(2);

#pragma unroll 1
    for (int kt = 0; kt < Kt; ++kt) {
        if (kt + 3 < Kt) STAGE(kt + 3);
        // wait until stage kt has landed; keep up to 3 stages (12 loads) in flight
        const int rem = Kt - 1 - kt;
        if (rem >= 3)      asm volatile("s_waitcnt vmcnt(12)" ::: "memory");
        else if (rem == 2) asm volatile("s_waitcnt vmcnt(8)" ::: "memory");
        else if (rem == 1) asm volatile("s_waitcnt vmcnt(4)" ::: "memory");
        else               asm volatile("s_waitcnt vmcnt(0)" ::: "memory");
        __builtin_amdgcn_s_barrier();          // all waves' stage-kt visible
        __builtin_amdgcn_sched_barrier(0);     // no reads hoisted above

        const char* bufp = smem + (kt & 3) * 32768;
        bf16x8 a[8], b[4];
#pragma unroll
        for (int m = 0; m < 8; m++) a[m] = *(const bf16x8*)(bufp + offA + m * 1024);
#pragma unroll
        for (int n = 0; n < 4; n++) b[n] = *(const bf16x8*)(bufp + offB + n * 1024);
        asm volatile("s_waitcnt lgkmcnt(0)" ::: "memory");  // reads serviced before buffer freed
        __builtin_amdgcn_sched_barrier(0);
        __builtin_amdgcn_s_barrier();          // buf[kt&3] now free for overwrite
        __builtin_amdgcn_sched_barrier(0);     // no stage sunk above this point

        __builtin_amdgcn_s_setprio(1);
#pragma unroll
        for (int m = 0; m < 8; m++)
#pragma unroll
            for (int n = 0; n < 4; n++)
                acc[m][n] = __builtin_amdgcn_mfma_f32_16x16x32_bf16(a[m], b[n], acc[m][n], 0, 0, 0);
        __builtin_amdgcn_s_setprio(0);
    }
#undef STAGE

    // epilogue: frag row = (l>>4)*4 + r, col = l&15
    const int row0 = by * 256 + wr * 128 + ((l >> 4) << 2);
    const int col0 = bx * 256 + wc * 64 + (l & 15);
    const int seg = bx >> 1;  // EPI4: 512-col segment (256-tile never straddles)
    const size_t segoff = (size_t)seg * M * 512;
#pragma unroll
    for (int n = 0; n < 4; n++) {
        const int col = col0 + n * 16;
        const float bv = bias[col];
#pragma unroll
        for (int m = 0; m < 8; m++) {
            const int rowb = row0 + m * 16;
#pragma unroll
            for (int r = 0; r < 4; r++) {
                float vv = acc[m][n][r] + bv;
                size_t idx = (size_t)(rowb + r) * N + col;
                if constexpr (EPI == 2) {
                    vv = vv > 0.f ? vv : 0.f;
                    out16[idx] = f2bf(vv);
                } else if constexpr (EPI == 3) {
                    vv += bf2f(res16[idx]);
                    out16[idx] = f2bf(vv);
                } else if constexpr (EPI == 4) {
                    if (seg < 2) vv = vv > 0.f ? vv + 1.f : __expf(vv);
                    out16[segoff + (size_t)(rowb + r) * 512 + (col & 511)] = f2bf(vv);
                } else {
                    out16[idx] = f2bf(vv);
                }
            }
        }
    }
}

// ---------------- kv partial reduction ----------------
__global__ __launch_bounds__(256) void kv_partial(
    const ushort* __restrict__ km, const ushort* __restrict__ v,
    float* __restrict__ kvp, float* __restrict__ ksump, int S) {
    __shared__ ushort kms[32 * 64];
    __shared__ ushort vs[32 * 64];
    const int t = threadIdx.x;
    const int bh = blockIdx.y, b = bh >> 3, h = bh & 7;
    const int d0 = (t >> 4) * 4, e0 = (t & 15) * 4;
    float acc[4][4] = {};
    float ks = 0.f;
    const int s_base = blockIdx.x * 512;
    const int r = t >> 3, c8 = (t & 7) * 8;
    for (int s0 = 0; s0 < 512; s0 += 32) {
        size_t grow = ((size_t)b * S + s_base + s0 + r) * 512 + h * 64 + c8;
        *(uint4*)&kms[r * 64 + c8] = *(const uint4*)&km[grow];
        *(uint4*)&vs[r * 64 + c8] = *(const uint4*)&v[grow];
        __syncthreads();
#pragma unroll 4
        for (int s = 0; s < 32; ++s) {
            ushort4 ka = *(const ushort4*)&kms[s * 64 + d0];
            ushort4 vb = *(const ushort4*)&vs[s * 64 + e0];
            float a0 = bf2f(ka.x), a1 = bf2f(ka.y), a2 = bf2f(ka.z), a3 = bf2f(ka.w);
            float b0 = bf2f(vb.x), b1 = bf2f(vb.y), b2 = bf2f(vb.z), b3 = bf2f(vb.w);
            acc[0][0] += a0 * b0; acc[0][1] += a0 * b1; acc[0][2] += a0 * b2; acc[0][3] += a0 * b3;
            acc[1][0] += a1 * b0; acc[1][1] += a1 * b1; acc[1][2] += a1 * b2; acc[1][3] += a1 * b3;
            acc[2][0] += a2 * b0; acc[2][1] += a2 * b1; acc[2][2] += a2 * b2; acc[2][3] += a2 * b3;
            acc[3][0] += a3 * b0; acc[3][1] += a3 * b1; acc[3][2] += a3 * b2; acc[3][3] += a3 * b3;
            if (t < 64) ks += bf2f(kms[s * 64 + t]);
        }
        __syncthreads();
    }
    float* dst = kvp + ((size_t)bh * 16 + blockIdx.x) * 4096;
#pragma unroll
    for (int i = 0; i < 4; i++)
#pragma unroll
        for (int j = 0; j < 4; j++)
            dst[(d0 + i) * 64 + e0 + j] = acc[i][j];
    if (t < 64) ksump[((size_t)bh * 16 + blockIdx.x) * 64 + t] = ks;
}

// reduce partials; kv emitted TRANSPOSED per head as bf16: kvt[bh][e][d]
__global__ void kv_reduce(const float* __restrict__ kvp, const float* __restrict__ ksump,
                          ushort* __restrict__ kvt, float* __restrict__ ksum) {
    int i = blockIdx.x * 256 + threadIdx.x;
    if (i < 32 * 4096) {
        int bh = i >> 12, de = i & 4095;
        int d = de >> 6, e = de & 63;
        float s = 0.f;
#pragma unroll
        for (int c = 0; c < 16; ++c) s += kvp[((size_t)bh * 16 + c) * 4096 + de];
        kvt[(size_t)bh * 4096 + e * 64 + d] = f2bf(s);
    } else {
        int j = i - 32 * 4096;
        if (j < 32 * 64) {
            int bh = j >> 6, d = j & 63;
            float s = 0.f;
#pragma unroll
            for (int c = 0; c < 16; ++c) s += ksump[((size_t)bh * 16 + c) * 64 + d];
            ksum[j] = s;
        }
    }
}

// ---------------- attn via MFMA: per (b,h) attn = qm[S,64] @ kv[64,64], * z ----------------
__global__ __launch_bounds__(256) void attn_mfma(
    const ushort* __restrict__ qm, const ushort* __restrict__ kvt,
    const float* __restrict__ ksum, ushort* __restrict__ attnE, int S) {
    __shared__ ushort As[128 * 128];
    __shared__ ushort Bs[128 * 64];
    __shared__ float zbuf[128][2];
    __shared__ float ks2[128];
    const int t = threadIdx.x, w = t >> 6, l = t & 63;
    const int cx = blockIdx.x, by = blockIdx.y;
    const int b = (by * 128) / S;
    const int h0 = cx * 2;
    const size_t arow0 = (size_t)(by * 128) * 512 + cx * 128;

#pragma unroll
    for (int rd = 0; rd < 8; ++rd) {
        const ushort* g = qm + arow0 + (size_t)(rd * 16 + w * 4 + (l >> 4)) * 512 + (l & 15) * 8;
        gload16(g, (char*)As + rd * 4096 + w * 1024);
    }
    const ushort* kvbase = kvt + (size_t)(b * 8 + h0) * 4096;
#pragma unroll
    for (int rd = 0; rd < 4; ++rd) {
        const ushort* g = kvbase + (rd * 32 + w * 8 + (l >> 3)) * 64 + (l & 7) * 8;
        gload16(g, (char*)Bs + rd * 4096 + w * 1024);
    }
    if (t < 128) ks2[t] = ksum[(b * 8 + h0) * 64 + t];
    __syncthreads();

    {
        const int r = t >> 1, hh = t & 1;
        float den = 0.f;
#pragma unroll
        for (int d0 = 0; d0 < 64; d0 += 8) {
            bf16x8 qv = *(const bf16x8*)&As[r * 128 + hh * 64 + d0];
#pragma unroll
            for (int j = 0; j < 8; j++) den += bf2f((ushort)qv[j]) * ks2[hh * 64 + d0 + j];
        }
        zbuf[r][hh] = 1.0f / (den + 1e-6f);
    }

    const int wr = w >> 1, wc = w & 1;
    const int ar = wr * 64 + (l & 15);
    const int br = wc * 64 + (l & 15);
    const int ko = (l >> 4) * 8;
    f32x4 acc[4][4] = {};
#pragma unroll
    for (int ks_ = 0; ks_ < 2; ++ks_) {
        bf16x8 a[4], bb[4];
#pragma unroll
        for (int m = 0; m < 4; m++)
            a[m] = *(const bf16x8*)&As[(ar + m * 16) * 128 + wc * 64 + ks_ * 32 + ko];
#pragma unroll
        for (int n = 0; n < 4; n++)
            bb[n] = *(const bf16x8*)&Bs[(br + n * 16) * 64 + ks_ * 32 + ko];
#pragma unroll
        for (int m = 0; m < 4; m++)
#pragma unroll
            for (int n = 0; n < 4; n++)
                acc[m][n] = __builtin_amdgcn_mfma_f32_16x16x32_bf16(a[m], bb[n], acc[m][n], 0, 0, 0);
    }
    __syncthreads();

    const int row0l = wr * 64 + ((l >> 4) << 2);
    ushort* outbase = attnE + (size_t)(by * 128) * 512 + cx * 128;
#pragma unroll
    for (int n = 0; n < 4; n++) {
#pragma unroll
        for (int m = 0; m < 4; m++) {
#pragma unroll
            for (int r = 0; r < 4; r++) {
                int rl = row0l + m * 16 + r;
                float z = zbuf[rl][wc];
                outbase[(size_t)rl * 512 + wc * 64 + n * 16 + (l & 15)] = f2bf(acc[m][n][r] * z);
            }
        }
    }
}

// ---------------- LayerNorm over bf16 input ----------------
template <int OUT32>
__global__ __launch_bounds__(256) void ln_bf16(
    const ushort* __restrict__ in, const float* __restrict__ g, const float* __restrict__ be,
    void* __restrict__ outp, int Mrows) {
    const int w = threadIdx.x >> 6, l = threadIdx.x & 63;
    const int row = blockIdx.x * 4 + w;
    if (row >= Mrows) return;
    const ushort* rp = in + (size_t)row * 512;
    uint4 u = *(const uint4*)&rp[l * 8];
    float x[8];
    x[0] = bf2f((ushort)(u.x & 0xffff)); x[1] = bf2f((ushort)(u.x >> 16));
    x[2] = bf2f((ushort)(u.y & 0xffff)); x[3] = bf2f((ushort)(u.y >> 16));
    x[4] = bf2f((ushort)(u.z & 0xffff)); x[5] = bf2f((ushort)(u.z >> 16));
    x[6] = bf2f((ushort)(u.w & 0xffff)); x[7] = bf2f((ushort)(u.w >> 16));
    float s = 0.f, ss = 0.f;
#pragma unroll
    for (int j = 0; j < 8; j++) { s += x[j]; ss += x[j] * x[j]; }
#pragma unroll
    for (int o = 1; o < 64; o <<= 1) {
        s += __shfl_xor(s, o, 64);
        ss += __shfl_xor(ss, o, 64);
    }
    float mean = s * (1.f / 512.f);
    float var = ss * (1.f / 512.f) - mean * mean;
    float rstd = rsqrtf(var + 1e-5f);
    float4 g0 = *(const float4*)&g[l * 8], g1v = *(const float4*)&g[l * 8 + 4];
    float4 b0 = *(const float4*)&be[l * 8], b1v = *(const float4*)&be[l * 8 + 4];
    float o0[8];
    o0[0] = (x[0] - mean) * rstd * g0.x + b0.x;
    o0[1] = (x[1] - mean) * rstd * g0.y + b0.y;
    o0[2] = (x[2] - mean) * rstd * g0.z + b0.z;
    o0[3] = (x[3] - mean) * rstd * g0.w + b0.w;
    o0[4] = (x[4] - mean) * rstd * g1v.x + b1v.x;
    o0[5] = (x[5] - mean) * rstd * g1v.y + b1v.y;
    o0[6] = (x[6] - mean) * rstd * g1v.z + b1v.z;
    o0[7] = (x[7] - mean) * rstd * g1v.w + b1v.w;
    if constexpr (OUT32) {
        float* op = (float*)outp + (size_t)row * 512;
        *(float4*)&op[l * 8] = make_float4(o0[0], o0[1], o0[2], o0[3]);
        *(float4*)&op[l * 8 + 4] = make_float4(o0[4], o0[5], o0[6], o0[7]);
    } else {
        ushort* op = (ushort*)outp + (size_t)row * 512;
        ushort4 u0, u1;
        u0.x = f2bf(o0[0]); u0.y = f2bf(o0[1]); u0.z = f2bf(o0[2]); u0.w = f2bf(o0[3]);
        u1.x = f2bf(o0[4]); u1.y = f2bf(o0[5]); u1.z = f2bf(o0[6]); u1.w = f2bf(o0[7]);
        *(ushort4*)&op[l * 8] = u0;
        *(ushort4*)&op[l * 8 + 4] = u1;
    }
}

extern "C" void kernel_launch(void* const* d_in, const int* in_sizes, int n_in,
                              void* d_out, int out_size, void* d_ws, size_t ws_size,
                              hipStream_t stream) {
    const int B = 4, S = 8192, E = 512, F = 2048;
    const int M = B * S;  // 32768
    const size_t SZ = (size_t)M * E * 2;  // 32 MiB
    const int SMEM = 131072;

    const float* src = (const float*)d_in[0];
    const float* Wq = (const float*)d_in[1];  const float* bq = (const float*)d_in[2];
    const float* Wk = (const float*)d_in[3];  const float* bk = (const float*)d_in[4];
    const float* Wv = (const float*)d_in[5];  const float* bv = (const float*)d_in[6];
    const float* Wo = (const float*)d_in[7];  const float* bo = (const float*)d_in[8];
    const float* W1 = (const float*)d_in[9];  const float* b1 = (const float*)d_in[10];
    const float* W2 = (const float*)d_in[11]; const float* b2 = (const float*)d_in[12];
    const float* g1 = (const float*)d_in[13]; const float* be1 = (const float*)d_in[14];
    const float* g2 = (const float*)d_in[15]; const float* be2 = (const float*)d_in[16];

    char* ws = (char*)d_ws;
    ushort* qm    = (ushort*)(ws + 0 * SZ);
    ushort* km    = (ushort*)(ws + 1 * SZ);
    ushort* v     = (ushort*)(ws + 2 * SZ);
    ushort* src16 = (ushort*)(ws + 3 * SZ);
    ushort* x16   = (ushort*)(ws + 4 * SZ);
    ushort* z16   = (ushort*)(ws + 5 * SZ);
    char*   tail  = ws + 6 * SZ;
    float*  kvp   = (float*)(tail);
    float*  ksump = (float*)(tail + 8388608);
    ushort* kvt   = (ushort*)(tail + 8519680);
    float*  ksum  = (float*)(tail + 8781824);
    float*  bqkv  = (float*)(tail + 8790016);
    ushort* wqkv  = (ushort*)(tail + 8796160);
    ushort* wot   = (ushort*)(tail + 10369024);
    ushort* w1t   = (ushort*)(tail + 10893312);
    ushort* w2t   = (ushort*)(tail + 12990464);
    ushort* attnE = km;
    ushort* y16   = v;
    ushort* hbuf  = (ushort*)(ws + 0);

    // allow 128 KB dynamic LDS on the GEMM instantiations (idempotent)
    hipFuncSetAttribute((const void*)gemm256<2>, hipFuncAttributeMaxDynamicSharedMemorySize, SMEM);
    hipFuncSetAttribute((const void*)gemm256<3>, hipFuncAttributeMaxDynamicSharedMemorySize, SMEM);
    hipFuncSetAttribute((const void*)gemm256<4>, hipFuncAttributeMaxDynamicSharedMemorySize, SMEM);

    // 1) converts
    conv_bf16<<<dim3((M * E / 4 + 255) / 256), 256, 0, stream>>>(src, src16, M * E / 4);
    wconv_t<<<dim3(E / 32, E / 32), 256, 0, stream>>>(Wq, wqkv, E, E);
    wconv_t<<<dim3(E / 32, E / 32), 256, 0, stream>>>(Wk, wqkv + 512 * 512, E, E);
    wconv_t<<<dim3(E / 32, E / 32), 256, 0, stream>>>(Wv, wqkv + 1024 * 512, E, E);
    wconv_t<<<dim3(E / 32, E / 32), 256, 0, stream>>>(Wo, wot, E, E);
    wconv_t<<<dim3(F / 32, E / 32), 256, 0, stream>>>(W1, w1t, E, F);
    wconv_t<<<dim3(E / 32, F / 32), 256, 0, stream>>>(W2, w2t, F, E);
    biascat<<<dim3(6), 256, 0, stream>>>(bq, bk, bv, bqkv);

    // 2) fused QKV GEMM (N=1536; elu+1 on q,k segments)
    gemm256<4><<<dim3(6 * 128), 512, SMEM, stream>>>(src16, wqkv, bqkv, nullptr, qm, M, 1536, E, 6);

    // 3) kv / ksum reduction
    kv_partial<<<dim3(16, 32), 256, 0, stream>>>(km, v, kvp, ksump, S);
    kv_reduce<<<dim3((32 * 4096 + 32 * 64 + 255) / 256), 256, 0, stream>>>(kvp, ksump, kvt, ksum);

    // 4) attention combine (MFMA)
    attn_mfma<<<dim3(4, M / 128), 256, 0, stream>>>(qm, kvt, ksum, attnE, S);

    // 5) output proj + bf16 residual, then LN -> x16
    gemm256<3><<<dim3(2 * 128), 512, SMEM, stream>>>(attnE, wot, bo, src16, y16, M, E, E, 2);
    ln_bf16<0><<<dim3(M / 4), 256, 0, stream>>>(y16, g1, be1, x16, M);

    // 6) FFN
    gemm256<2><<<dim3(8 * 128), 512, SMEM, stream>>>(x16, w1t, b1, nullptr, hbuf, M, F, E, 8);
    gemm256<3><<<dim3(2 * 128), 512, SMEM, stream>>>(hbuf, w2t, b2, x16, z16, M, E, F, 2);
    ln_bf16<1><<<dim3(M / 4), 256, 0, stream>>>(z16, g2, be2, (float*)d_out, M);
}

// Round 5
// 398.088 us; speedup vs baseline: 1.2041x; 1.2041x over previous
//
#include <hip/hip_runtime.h>
#include <hip/hip_bf16.h>

typedef __attribute__((ext_vector_type(8))) short bf16x8;
typedef __attribute__((ext_vector_type(4))) float f32x4;

__device__ inline ushort f2bf(float f) {
    uint u = __float_as_uint(f);
    u += 0x7fff + ((u >> 16) & 1);
    return (ushort)(u >> 16);
}
__device__ inline float bf2f(ushort h) {
    return __uint_as_float(((uint)h) << 16);
}

__device__ inline void gload16(const void* g, void* lds) {
    __builtin_amdgcn_global_load_lds(
        (const __attribute__((address_space(1))) void*)g,
        (__attribute__((address_space(3))) void*)lds, 16, 0, 0);
}

// ---------------- converts ----------------
__global__ void conv_bf16(const float* __restrict__ in, ushort* __restrict__ out, int n4) {
    int i = blockIdx.x * 256 + threadIdx.x;
    if (i >= n4) return;
    float4 a = ((const float4*)in)[i];
    ushort4 o;
    o.x = f2bf(a.x); o.y = f2bf(a.y); o.z = f2bf(a.z); o.w = f2bf(a.w);
    ((ushort4*)out)[i] = o;
}

// in: fp32 [K,N] -> out: bf16 [N,K]
__global__ void wconv_t(const float* __restrict__ in, ushort* __restrict__ out, int K, int N) {
    __shared__ float tile[32][33];
    int kb = blockIdx.y * 32, nb = blockIdx.x * 32;
    int tx = threadIdx.x & 31, ty = threadIdx.x >> 5;  // 32 x 8
#pragma unroll
    for (int i = 0; i < 4; i++)
        tile[ty + i * 8][tx] = in[(size_t)(kb + ty + i * 8) * N + nb + tx];
    __syncthreads();
#pragma unroll
    for (int i = 0; i < 4; i++) {
        int n = nb + ty + i * 8, k = kb + tx;
        out[(size_t)n * K + k] = f2bf(tile[tx][ty + i * 8]);
    }
}

__global__ void biascat(const float* __restrict__ a, const float* __restrict__ b,
                        const float* __restrict__ c, float* __restrict__ o) {
    int i = blockIdx.x * 256 + threadIdx.x;
    if (i < 512) o[i] = a[i];
    else if (i < 1024) o[i] = b[i - 512];
    else if (i < 1536) o[i] = c[i - 1024];
}

// ============ 256x256 deep-pipelined GEMM: C = A[M,K] @ Bt[N,K]^T + bias ============
// 512 threads (8 waves, 2Mx4N), BK=32, 4-buffer LDS rotation (128 KB dynamic),
// 3-deep prefetch with counted vmcnt (never 0 in main loop), PHASED ds_read/MFMA
// interleave inside each K-tile (reads for phase p+1 overlap MFMAs of phase p;
// backend inserts counted lgkmcnt since DS returns are in-order).
// Barrier safety: barrier#1 (after vmcnt) = stage kt visible to all waves before
// any ds_read; barrier#2 (end of iter) = all waves' ds_reads of buf[kt&3] complete
// (reads complete-by-use before their MFMAs) before STAGE(kt+4) next iter overwrites it.
// EPI: 2 = relu bf16; 3 = bf16 residual add; 4 = fused QKV (seg<2: elu+1) -> [3][M][512]
template <int EPI>
__global__ __launch_bounds__(512, 2) void gemm256(
    const ushort* __restrict__ A, const ushort* __restrict__ Bt,
    const float* __restrict__ bias, const ushort* __restrict__ res16,
    ushort* __restrict__ out16, int M, int N, int K, int nbx) {
    extern __shared__ char smem[];  // 4 * 32768
    const int t = threadIdx.x;
    const int w = t >> 6, l = t & 63;
    const int wr = w >> 2, wc = w & 3;
    // XCD-chunked bijective swizzle (grid divisible by 8)
    const int nwg = gridDim.x;
    const int cpx = nwg >> 3;
    const int swz = (blockIdx.x & 7) * cpx + (blockIdx.x >> 3);
    const int bx = swz % nbx, by = swz / nbx;

    // staging source: thread t covers storage bytes t*16 of each 8KB round.
    // storage row = t>>2 (+128 for second round), storage chunk = t&3;
    // source logical chunk = (t&3) ^ ((row>>1)&3)   (XOR swizzle, rule #21: dest linear)
    const int sc = (t & 3) ^ ((t >> 3) & 3);
    const ushort* gA0 = A + (size_t)(by * 256 + (t >> 2)) * K + sc * 8;
    const ushort* gA1 = gA0 + (size_t)128 * K;
    const ushort* gB0 = Bt + (size_t)(bx * 256 + (t >> 2)) * K + sc * 8;
    const ushort* gB1 = gB0 + (size_t)128 * K;

#define STAGE(kt)                                             \
    {                                                         \
        char* Lb = smem + ((kt) & 3) * 32768 + (w << 10);     \
        const int ko_ = (kt) * 32;                            \
        gload16(gA0 + ko_, Lb);                               \
        gload16(gA1 + ko_, Lb + 8192);                        \
        gload16(gB0 + ko_, Lb + 16384);                       \
        gload16(gB1 + ko_, Lb + 24576);                       \
    }

    f32x4 acc[8][4] = {};
    const int Kt = K >> 5;

    // ds_read offsets (constant per thread): logical (row, kchunk=l>>4) -> swizzled chunk
    const int R0a = wr * 128 + (l & 15);
    const int offA = R0a * 64 + (((l >> 4) ^ ((R0a >> 1) & 3)) << 4);
    const int R0b = wc * 64 + (l & 15);
    const int offB = 16384 + R0b * 64 + (((l >> 4) ^ ((R0b >> 1) & 3)) << 4);

    // prologue: 3 K-tiles in flight
    STAGE(0); STAGE(1); STAGE(2);

#pragma unroll 1
    for (int kt = 0; kt < Kt; ++kt) {
        if (kt + 3 < Kt) STAGE(kt + 3);
        // wait until stage kt has landed; keep up to 3 stages (12 loads) in flight
        const int rem = Kt - 1 - kt;
        if (rem >= 3)      asm volatile("s_waitcnt vmcnt(12)" ::: "memory");
        else if (rem == 2) asm volatile("s_waitcnt vmcnt(8)" ::: "memory");
        else if (rem == 1) asm volatile("s_waitcnt vmcnt(4)" ::: "memory");
        else               asm volatile("s_waitcnt vmcnt(0)" ::: "memory");
        __builtin_amdgcn_s_barrier();          // all waves' stage-kt visible
        __builtin_amdgcn_sched_barrier(0);     // no reads hoisted above

        const char* bufp = smem + (kt & 3) * 32768;
        bf16x8 a[8], b[4];
        b[0] = *(const bf16x8*)(bufp + offB);
        b[1] = *(const bf16x8*)(bufp + offB + 1024);
        b[2] = *(const bf16x8*)(bufp + offB + 2048);
        b[3] = *(const bf16x8*)(bufp + offB + 3072);
        a[0] = *(const bf16x8*)(bufp + offA);
        a[1] = *(const bf16x8*)(bufp + offA + 1024);
        __builtin_amdgcn_sched_barrier(0);
#pragma unroll
        for (int p = 0; p < 4; ++p) {
            if (p < 3) {
                a[2 * p + 2] = *(const bf16x8*)(bufp + offA + (2 * p + 2) * 1024);
                a[2 * p + 3] = *(const bf16x8*)(bufp + offA + (2 * p + 3) * 1024);
                __builtin_amdgcn_sched_barrier(0);
            }
            __builtin_amdgcn_s_setprio(1);
#pragma unroll
            for (int mm = 0; mm < 2; ++mm)
#pragma unroll
                for (int n = 0; n < 4; ++n)
                    acc[2 * p + mm][n] = __builtin_amdgcn_mfma_f32_16x16x32_bf16(
                        a[2 * p + mm], b[n], acc[2 * p + mm][n], 0, 0, 0);
            __builtin_amdgcn_s_setprio(0);
            __builtin_amdgcn_sched_barrier(0);
        }
        __builtin_amdgcn_s_barrier();          // buf[kt&3] free for STAGE(kt+4) next iter
        __builtin_amdgcn_sched_barrier(0);     // no stage sunk above this point
    }
#undef STAGE

    // epilogue: frag row = (l>>4)*4 + r, col = l&15; n INNERMOST so the four
    // 32B store groups filling one 128B line issue back-to-back (full-sector merge).
    const int row0 = by * 256 + wr * 128 + ((l >> 4) << 2);
    const int col0 = bx * 256 + wc * 64 + (l & 15);
    const int seg = bx >> 1;  // EPI4: 512-col segment (256-tile never straddles)
    const size_t segoff = (size_t)seg * M * 512;
    const int c511 = col0 & 511;
    float bv[4];
#pragma unroll
    for (int n = 0; n < 4; n++) bv[n] = bias[col0 + n * 16];
#pragma unroll
    for (int m = 0; m < 8; m++) {
#pragma unroll
        for (int r = 0; r < 4; r++) {
            const int row = row0 + m * 16 + r;
            const size_t base = (size_t)row * N + col0;
#pragma unroll
            for (int n = 0; n < 4; n++) {
                float vv = acc[m][n][r] + bv[n];
                if constexpr (EPI == 2) {
                    vv = vv > 0.f ? vv : 0.f;
                    out16[base + n * 16] = f2bf(vv);
                } else if constexpr (EPI == 3) {
                    vv += bf2f(res16[base + n * 16]);
                    out16[base + n * 16] = f2bf(vv);
                } else if constexpr (EPI == 4) {
                    if (seg < 2) vv = vv > 0.f ? vv + 1.f : __expf(vv);
                    out16[segoff + (size_t)row * 512 + c511 + n * 16] = f2bf(vv);
                } else {
                    out16[base + n * 16] = f2bf(vv);
                }
            }
        }
    }
}

// ---------------- kv partial reduction ----------------
__global__ __launch_bounds__(256) void kv_partial(
    const ushort* __restrict__ km, const ushort* __restrict__ v,
    float* __restrict__ kvp, float* __restrict__ ksump, int S) {
    __shared__ ushort kms[32 * 64];
    __shared__ ushort vs[32 * 64];
    const int t = threadIdx.x;
    const int bh = blockIdx.y, b = bh >> 3, h = bh & 7;
    const int d0 = (t >> 4) * 4, e0 = (t & 15) * 4;
    float acc[4][4] = {};
    float ks = 0.f;
    const int s_base = blockIdx.x * 512;
    const int r = t >> 3, c8 = (t & 7) * 8;
    for (int s0 = 0; s0 < 512; s0 += 32) {
        size_t grow = ((size_t)b * S + s_base + s0 + r) * 512 + h * 64 + c8;
        *(uint4*)&kms[r * 64 + c8] = *(const uint4*)&km[grow];
        *(uint4*)&vs[r * 64 + c8] = *(const uint4*)&v[grow];
        __syncthreads();
#pragma unroll 4
        for (int s = 0; s < 32; ++s) {
            ushort4 ka = *(const ushort4*)&kms[s * 64 + d0];
            ushort4 vb = *(const ushort4*)&vs[s * 64 + e0];
            float a0 = bf2f(ka.x), a1 = bf2f(ka.y), a2 = bf2f(ka.z), a3 = bf2f(ka.w);
            float b0 = bf2f(vb.x), b1 = bf2f(vb.y), b2 = bf2f(vb.z), b3 = bf2f(vb.w);
            acc[0][0] += a0 * b0; acc[0][1] += a0 * b1; acc[0][2] += a0 * b2; acc[0][3] += a0 * b3;
            acc[1][0] += a1 * b0; acc[1][1] += a1 * b1; acc[1][2] += a1 * b2; acc[1][3] += a1 * b3;
            acc[2][0] += a2 * b0; acc[2][1] += a2 * b1; acc[2][2] += a2 * b2; acc[2][3] += a2 * b3;
            acc[3][0] += a3 * b0; acc[3][1] += a3 * b1; acc[3][2] += a3 * b2; acc[3][3] += a3 * b3;
            if (t < 64) ks += bf2f(kms[s * 64 + t]);
        }
        __syncthreads();
    }
    float* dst = kvp + ((size_t)bh * 16 + blockIdx.x) * 4096;
#pragma unroll
    for (int i = 0; i < 4; i++)
#pragma unroll
        for (int j = 0; j < 4; j++)
            dst[(d0 + i) * 64 + e0 + j] = acc[i][j];
    if (t < 64) ksump[((size_t)bh * 16 + blockIdx.x) * 64 + t] = ks;
}

// reduce partials; kv emitted TRANSPOSED per head as bf16: kvt[bh][e][d]
__global__ void kv_reduce(const float* __restrict__ kvp, const float* __restrict__ ksump,
                          ushort* __restrict__ kvt, float* __restrict__ ksum) {
    int i = blockIdx.x * 256 + threadIdx.x;
    if (i < 32 * 4096) {
        int bh = i >> 12, de = i & 4095;
        int d = de >> 6, e = de & 63;
        float s = 0.f;
#pragma unroll
        for (int c = 0; c < 16; ++c) s += kvp[((size_t)bh * 16 + c) * 4096 + de];
        kvt[(size_t)bh * 4096 + e * 64 + d] = f2bf(s);
    } else {
        int j = i - 32 * 4096;
        if (j < 32 * 64) {
            int bh = j >> 6, d = j & 63;
            float s = 0.f;
#pragma unroll
            for (int c = 0; c < 16; ++c) s += ksump[((size_t)bh * 16 + c) * 64 + d];
            ksum[j] = s;
        }
    }
}

// ---------------- attn via MFMA: per (b,h) attn = qm[S,64] @ kv[64,64], * z ----------------
__global__ __launch_bounds__(256) void attn_mfma(
    const ushort* __restrict__ qm, const ushort* __restrict__ kvt,
    const float* __restrict__ ksum, ushort* __restrict__ attnE, int S) {
    __shared__ ushort As[128 * 128];
    __shared__ ushort Bs[128 * 64];
    __shared__ float zbuf[128][2];
    __shared__ float ks2[128];
    const int t = threadIdx.x, w = t >> 6, l = t & 63;
    const int cx = blockIdx.x, by = blockIdx.y;
    const int b = (by * 128) / S;
    const int h0 = cx * 2;
    const size_t arow0 = (size_t)(by * 128) * 512 + cx * 128;

#pragma unroll
    for (int rd = 0; rd < 8; ++rd) {
        const ushort* g = qm + arow0 + (size_t)(rd * 16 + w * 4 + (l >> 4)) * 512 + (l & 15) * 8;
        gload16(g, (char*)As + rd * 4096 + w * 1024);
    }
    const ushort* kvbase = kvt + (size_t)(b * 8 + h0) * 4096;
#pragma unroll
    for (int rd = 0; rd < 4; ++rd) {
        const ushort* g = kvbase + (rd * 32 + w * 8 + (l >> 3)) * 64 + (l & 7) * 8;
        gload16(g, (char*)Bs + rd * 4096 + w * 1024);
    }
    if (t < 128) ks2[t] = ksum[(b * 8 + h0) * 64 + t];
    __syncthreads();

    {
        const int r = t >> 1, hh = t & 1;
        float den = 0.f;
#pragma unroll
        for (int d0 = 0; d0 < 64; d0 += 8) {
            bf16x8 qv = *(const bf16x8*)&As[r * 128 + hh * 64 + d0];
#pragma unroll
            for (int j = 0; j < 8; j++) den += bf2f((ushort)qv[j]) * ks2[hh * 64 + d0 + j];
        }
        zbuf[r][hh] = 1.0f / (den + 1e-6f);
    }

    const int wr = w >> 1, wc = w & 1;
    const int ar = wr * 64 + (l & 15);
    const int br = wc * 64 + (l & 15);
    const int ko = (l >> 4) * 8;
    f32x4 acc[4][4] = {};
#pragma unroll
    for (int ks_ = 0; ks_ < 2; ++ks_) {
        bf16x8 a[4], bb[4];
#pragma unroll
        for (int m = 0; m < 4; m++)
            a[m] = *(const bf16x8*)&As[(ar + m * 16) * 128 + wc * 64 + ks_ * 32 + ko];
#pragma unroll
        for (int n = 0; n < 4; n++)
            bb[n] = *(const bf16x8*)&Bs[(br + n * 16) * 64 + ks_ * 32 + ko];
#pragma unroll
        for (int m = 0; m < 4; m++)
#pragma unroll
            for (int n = 0; n < 4; n++)
                acc[m][n] = __builtin_amdgcn_mfma_f32_16x16x32_bf16(a[m], bb[n], acc[m][n], 0, 0, 0);
    }
    __syncthreads();

    const int row0l = wr * 64 + ((l >> 4) << 2);
    ushort* outbase = attnE + (size_t)(by * 128) * 512 + cx * 128;
#pragma unroll
    for (int n = 0; n < 4; n++) {
#pragma unroll
        for (int m = 0; m < 4; m++) {
#pragma unroll
            for (int r = 0; r < 4; r++) {
                int rl = row0l + m * 16 + r;
                float z = zbuf[rl][wc];
                outbase[(size_t)rl * 512 + wc * 64 + n * 16 + (l & 15)] = f2bf(acc[m][n][r] * z);
            }
        }
    }
}

// ---------------- LayerNorm over bf16 input ----------------
template <int OUT32>
__global__ __launch_bounds__(256) void ln_bf16(
    const ushort* __restrict__ in, const float* __restrict__ g, const float* __restrict__ be,
    void* __restrict__ outp, int Mrows) {
    const int w = threadIdx.x >> 6, l = threadIdx.x & 63;
    const int row = blockIdx.x * 4 + w;
    if (row >= Mrows) return;
    const ushort* rp = in + (size_t)row * 512;
    uint4 u = *(const uint4*)&rp[l * 8];
    float x[8];
    x[0] = bf2f((ushort)(u.x & 0xffff)); x[1] = bf2f((ushort)(u.x >> 16));
    x[2] = bf2f((ushort)(u.y & 0xffff)); x[3] = bf2f((ushort)(u.y >> 16));
    x[4] = bf2f((ushort)(u.z & 0xffff)); x[5] = bf2f((ushort)(u.z >> 16));
    x[6] = bf2f((ushort)(u.w & 0xffff)); x[7] = bf2f((ushort)(u.w >> 16));
    float s = 0.f, ss = 0.f;
#pragma unroll
    for (int j = 0; j < 8; j++) { s += x[j]; ss += x[j] * x[j]; }
#pragma unroll
    for (int o = 1; o < 64; o <<= 1) {
        s += __shfl_xor(s, o, 64);
        ss += __shfl_xor(ss, o, 64);
    }
    float mean = s * (1.f / 512.f);
    float var = ss * (1.f / 512.f) - mean * mean;
    float rstd = rsqrtf(var + 1e-5f);
    float4 g0 = *(const float4*)&g[l * 8], g1v = *(const float4*)&g[l * 8 + 4];
    float4 b0 = *(const float4*)&be[l * 8], b1v = *(const float4*)&be[l * 8 + 4];
    float o0[8];
    o0[0] = (x[0] - mean) * rstd * g0.x + b0.x;
    o0[1] = (x[1] - mean) * rstd * g0.y + b0.y;
    o0[2] = (x[2] - mean) * rstd * g0.z + b0.z;
    o0[3] = (x[3] - mean) * rstd * g0.w + b0.w;
    o0[4] = (x[4] - mean) * rstd * g1v.x + b1v.x;
    o0[5] = (x[5] - mean) * rstd * g1v.y + b1v.y;
    o0[6] = (x[6] - mean) * rstd * g1v.z + b1v.z;
    o0[7] = (x[7] - mean) * rstd * g1v.w + b1v.w;
    if constexpr (OUT32) {
        float* op = (float*)outp + (size_t)row * 512;
        *(float4*)&op[l * 8] = make_float4(o0[0], o0[1], o0[2], o0[3]);
        *(float4*)&op[l * 8 + 4] = make_float4(o0[4], o0[5], o0[6], o0[7]);
    } else {
        ushort* op = (ushort*)outp + (size_t)row * 512;
        ushort4 u0, u1;
        u0.x = f2bf(o0[0]); u0.y = f2bf(o0[1]); u0.z = f2bf(o0[2]); u0.w = f2bf(o0[3]);
        u1.x = f2bf(o0[4]); u1.y = f2bf(o0[5]); u1.z = f2bf(o0[6]); u1.w = f2bf(o0[7]);
        *(ushort4*)&op[l * 8] = u0;
        *(ushort4*)&op[l * 8 + 4] = u1;
    }
}

extern "C" void kernel_launch(void* const* d_in, const int* in_sizes, int n_in,
                              void* d_out, int out_size, void* d_ws, size_t ws_size,
                              hipStream_t stream) {
    const int B = 4, S = 8192, E = 512, F = 2048;
    const int M = B * S;  // 32768
    const size_t SZ = (size_t)M * E * 2;  // 32 MiB
    const int SMEM = 131072;

    const float* src = (const float*)d_in[0];
    const float* Wq = (const float*)d_in[1];  const float* bq = (const float*)d_in[2];
    const float* Wk = (const float*)d_in[3];  const float* bk = (const float*)d_in[4];
    const float* Wv = (const float*)d_in[5];  const float* bv = (const float*)d_in[6];
    const float* Wo = (const float*)d_in[7];  const float* bo = (const float*)d_in[8];
    const float* W1 = (const float*)d_in[9];  const float* b1 = (const float*)d_in[10];
    const float* W2 = (const float*)d_in[11]; const float* b2 = (const float*)d_in[12];
    const float* g1 = (const float*)d_in[13]; const float* be1 = (const float*)d_in[14];
    const float* g2 = (const float*)d_in[15]; const float* be2 = (const float*)d_in[16];

    char* ws = (char*)d_ws;
    ushort* qm    = (ushort*)(ws + 0 * SZ);
    ushort* km    = (ushort*)(ws + 1 * SZ);
    ushort* v     = (ushort*)(ws + 2 * SZ);
    ushort* src16 = (ushort*)(ws + 3 * SZ);
    ushort* x16   = (ushort*)(ws + 4 * SZ);
    ushort* z16   = (ushort*)(ws + 5 * SZ);
    char*   tail  = ws + 6 * SZ;
    float*  kvp   = (float*)(tail);
    float*  ksump = (float*)(tail + 8388608);
    ushort* kvt   = (ushort*)(tail + 8519680);
    float*  ksum  = (float*)(tail + 8781824);
    float*  bqkv  = (float*)(tail + 8790016);
    ushort* wqkv  = (ushort*)(tail + 8796160);
    ushort* wot   = (ushort*)(tail + 10369024);
    ushort* w1t   = (ushort*)(tail + 10893312);
    ushort* w2t   = (ushort*)(tail + 12990464);
    ushort* attnE = km;
    ushort* y16   = v;
    ushort* hbuf  = (ushort*)(ws + 0);

    // allow 128 KB dynamic LDS on the GEMM instantiations (idempotent)
    hipFuncSetAttribute((const void*)gemm256<2>, hipFuncAttributeMaxDynamicSharedMemorySize, SMEM);
    hipFuncSetAttribute((const void*)gemm256<3>, hipFuncAttributeMaxDynamicSharedMemorySize, SMEM);
    hipFuncSetAttribute((const void*)gemm256<4>, hipFuncAttributeMaxDynamicSharedMemorySize, SMEM);

    // 1) converts
    conv_bf16<<<dim3((M * E / 4 + 255) / 256), 256, 0, stream>>>(src, src16, M * E / 4);
    wconv_t<<<dim3(E / 32, E / 32), 256, 0, stream>>>(Wq, wqkv, E, E);
    wconv_t<<<dim3(E / 32, E / 32), 256, 0, stream>>>(Wk, wqkv + 512 * 512, E, E);
    wconv_t<<<dim3(E / 32, E / 32), 256, 0, stream>>>(Wv, wqkv + 1024 * 512, E, E);
    wconv_t<<<dim3(E / 32, E / 32), 256, 0, stream>>>(Wo, wot, E, E);
    wconv_t<<<dim3(F / 32, E / 32), 256, 0, stream>>>(W1, w1t, E, F);
    wconv_t<<<dim3(E / 32, F / 32), 256, 0, stream>>>(W2, w2t, F, E);
    biascat<<<dim3(6), 256, 0, stream>>>(bq, bk, bv, bqkv);

    // 2) fused QKV GEMM (N=1536; elu+1 on q,k segments)
    gemm256<4><<<dim3(6 * 128), 512, SMEM, stream>>>(src16, wqkv, bqkv, nullptr, qm, M, 1536, E, 6);

    // 3) kv / ksum reduction
    kv_partial<<<dim3(16, 32), 256, 0, stream>>>(km, v, kvp, ksump, S);
    kv_reduce<<<dim3((32 * 4096 + 32 * 64 + 255) / 256), 256, 0, stream>>>(kvp, ksump, kvt, ksum);

    // 4) attention combine (MFMA)
    attn_mfma<<<dim3(4, M / 128), 256, 0, stream>>>(qm, kvt, ksum, attnE, S);

    // 5) output proj + bf16 residual, then LN -> x16
    gemm256<3><<<dim3(2 * 128), 512, SMEM, stream>>>(attnE, wot, bo, src16, y16, M, E, E, 2);
    ln_bf16<0><<<dim3(M / 4), 256, 0, stream>>>(y16, g1, be1, x16, M);

    // 6) FFN
    gemm256<2><<<dim3(8 * 128), 512, SMEM, stream>>>(x16, w1t, b1, nullptr, hbuf, M, F, E, 8);
    gemm256<3><<<dim3(2 * 128), 512, SMEM, stream>>>(hbuf, w2t, b2, x16, z16, M, E, F, 2);
    ln_bf16<1><<<dim3(M / 4), 256, 0, stream>>>(z16, g2, be2, (float*)d_out, M);
}

// Round 6
// 382.839 us; speedup vs baseline: 1.2521x; 1.0398x over previous
//
#include <hip/hip_runtime.h>
#include <hip/hip_bf16.h>

typedef __attribute__((ext_vector_type(8))) short bf16x8;
typedef __attribute__((ext_vector_type(4))) float f32x4;

__device__ inline ushort f2bf(float f) {
    uint u = __float_as_uint(f);
    u += 0x7fff + ((u >> 16) & 1);
    return (ushort)(u >> 16);
}
__device__ inline float bf2f(ushort h) {
    return __uint_as_float(((uint)h) << 16);
}

__device__ inline void gload16(const void* g, void* lds) {
    __builtin_amdgcn_global_load_lds(
        (const __attribute__((address_space(1))) void*)g,
        (__attribute__((address_space(3))) void*)lds, 16, 0, 0);
}

// ---------------- converts ----------------
__global__ void conv_bf16(const float* __restrict__ in, ushort* __restrict__ out, int n4) {
    int i = blockIdx.x * 256 + threadIdx.x;
    if (i >= n4) return;
    float4 a = ((const float4*)in)[i];
    ushort4 o;
    o.x = f2bf(a.x); o.y = f2bf(a.y); o.z = f2bf(a.z); o.w = f2bf(a.w);
    ((ushort4*)out)[i] = o;
}

// in: fp32 [K,N] -> out: bf16 [N,K]
__global__ void wconv_t(const float* __restrict__ in, ushort* __restrict__ out, int K, int N) {
    __shared__ float tile[32][33];
    int kb = blockIdx.y * 32, nb = blockIdx.x * 32;
    int tx = threadIdx.x & 31, ty = threadIdx.x >> 5;  // 32 x 8
#pragma unroll
    for (int i = 0; i < 4; i++)
        tile[ty + i * 8][tx] = in[(size_t)(kb + ty + i * 8) * N + nb + tx];
    __syncthreads();
#pragma unroll
    for (int i = 0; i < 4; i++) {
        int n = nb + ty + i * 8, k = kb + tx;
        out[(size_t)n * K + k] = f2bf(tile[tx][ty + i * 8]);
    }
}

__global__ void biascat(const float* __restrict__ a, const float* __restrict__ b,
                        const float* __restrict__ c, float* __restrict__ o) {
    int i = blockIdx.x * 256 + threadIdx.x;
    if (i < 512) o[i] = a[i];
    else if (i < 1024) o[i] = b[i - 512];
    else if (i < 1536) o[i] = c[i - 1024];
}

// ============ 256x256 deep-pipelined GEMM: C = A[M,K] @ Bt[N,K]^T + bias ============
// 512 threads (8 waves, 2Mx4N), BK=32, 4-buffer LDS rotation (128 KB dynamic),
// 3-deep prefetch with counted vmcnt, m201-style PHASE skeleton:
//   per phase: {issue ds_reads; issue half-stage; BARRIER; lgkmcnt(0); 16 MFMA}
// Overlap mechanism: reads issued before the barrier; each wave blocks on its OWN
// lgkmcnt(0), so early-serviced waves' MFMA clusters run while LDS returns later
// waves' reads (cross-wave MFMA || LDS overlap).
// Race safety:
//  - top barrier (after counted vmcnt): every wave's stage(kt) loads landed ->
//    buf[kt&3] fully valid before any ds_read of it.
//  - STAGE_H*(kt+3) writes buf[(kt+3)&3] == buf[(kt-1)&3]; issued after the top
//    barrier of tile kt, which is after every wave's phase-2 lgkmcnt(0) of tile
//    kt-1 -> all reads of buf[kt-1] completed. No overwrite race.
//  - vmcnt ladder: un-landed stages at tile-kt top are {kt,kt+1,kt+2} (4 loads
//    each); wait 8/4/0 by remaining-tile count so stage(kt) is always covered.
// EPI: 2 = relu bf16; 3 = bf16 residual add; 4 = fused QKV (seg<2: elu+1) -> [3][M][512]
template <int EPI>
__global__ __launch_bounds__(512, 2) void gemm256(
    const ushort* __restrict__ A, const ushort* __restrict__ Bt,
    const float* __restrict__ bias, const ushort* __restrict__ res16,
    ushort* __restrict__ out16, int M, int N, int K, int nbx) {
    extern __shared__ char smem[];  // 4 * 32768
    const int t = threadIdx.x;
    const int w = t >> 6, l = t & 63;
    const int wr = w >> 2, wc = w & 3;
    // XCD-chunked bijective swizzle (grid divisible by 8)
    const int nwg = gridDim.x;
    const int cpx = nwg >> 3;
    const int swz = (blockIdx.x & 7) * cpx + (blockIdx.x >> 3);
    const int bx = swz % nbx, by = swz / nbx;

    // staging source: thread t covers storage bytes t*16 of each 8KB quarter.
    // storage row = t>>2, storage chunk = t&3; source logical chunk = (t&3)^((row>>1)&3)
    const int sc = (t & 3) ^ ((t >> 3) & 3);
    const ushort* gA0 = A + (size_t)(by * 256 + (t >> 2)) * K + sc * 8;
    const ushort* gA1 = gA0 + (size_t)128 * K;
    const ushort* gB0 = Bt + (size_t)(bx * 256 + (t >> 2)) * K + sc * 8;
    const ushort* gB1 = gB0 + (size_t)128 * K;

#define STAGE_H0(kt)                                          \
    {                                                         \
        char* Lb = smem + ((kt) & 3) * 32768 + (w << 10);     \
        const int ko_ = (kt) * 32;                            \
        gload16(gA0 + ko_, Lb);                               \
        gload16(gB0 + ko_, Lb + 16384);                       \
    }
#define STAGE_H1(kt)                                          \
    {                                                         \
        char* Lb = smem + ((kt) & 3) * 32768 + (w << 10);     \
        const int ko_ = (kt) * 32;                            \
        gload16(gA1 + ko_, Lb + 8192);                        \
        gload16(gB1 + ko_, Lb + 24576);                       \
    }

    f32x4 acc[8][4] = {};
    const int Kt = K >> 5;

    // ds_read offsets (constant per thread): logical (row, kchunk=l>>4) -> swizzled chunk
    const int R0a = wr * 128 + (l & 15);
    const int offA = R0a * 64 + (((l >> 4) ^ ((R0a >> 1) & 3)) << 4);
    const int R0b = wc * 64 + (l & 15);
    const int offB = 16384 + R0b * 64 + (((l >> 4) ^ ((R0b >> 1) & 3)) << 4);

    // prologue: 3 K-tiles in flight (12 loads)
    STAGE_H0(0); STAGE_H1(0);
    STAGE_H0(1); STAGE_H1(1);
    STAGE_H0(2); STAGE_H1(2);

#pragma unroll 1
    for (int kt = 0; kt < Kt; ++kt) {
        const int rem = Kt - 1 - kt;
        if (rem >= 2)      asm volatile("s_waitcnt vmcnt(8)" ::: "memory");
        else if (rem == 1) asm volatile("s_waitcnt vmcnt(4)" ::: "memory");
        else               asm volatile("s_waitcnt vmcnt(0)" ::: "memory");
        __builtin_amdgcn_s_barrier();          // all waves' stage(kt) visible
        __builtin_amdgcn_sched_barrier(0);

        const char* bufp = smem + (kt & 3) * 32768;
        bf16x8 a[8], b[4];
        // ---- phase 1: issue reads (b0-3, a0-3) + half-stage, then barrier/consume
        b[0] = *(const bf16x8*)(bufp + offB);
        b[1] = *(const bf16x8*)(bufp + offB + 1024);
        b[2] = *(const bf16x8*)(bufp + offB + 2048);
        b[3] = *(const bf16x8*)(bufp + offB + 3072);
        a[0] = *(const bf16x8*)(bufp + offA);
        a[1] = *(const bf16x8*)(bufp + offA + 1024);
        a[2] = *(const bf16x8*)(bufp + offA + 2048);
        a[3] = *(const bf16x8*)(bufp + offA + 3072);
        if (kt + 3 < Kt) STAGE_H0(kt + 3);
        __builtin_amdgcn_sched_barrier(0);
        __builtin_amdgcn_s_barrier();
        asm volatile("s_waitcnt lgkmcnt(0)" ::: "memory");
        __builtin_amdgcn_sched_barrier(0);
        __builtin_amdgcn_s_setprio(1);
#pragma unroll
        for (int m = 0; m < 4; m++)
#pragma unroll
            for (int n = 0; n < 4; n++)
                acc[m][n] = __builtin_amdgcn_mfma_f32_16x16x32_bf16(a[m], b[n], acc[m][n], 0, 0, 0);
        __builtin_amdgcn_s_setprio(0);
        __builtin_amdgcn_sched_barrier(0);
        // ---- phase 2: issue reads (a4-7) + half-stage, then barrier/consume
        a[4] = *(const bf16x8*)(bufp + offA + 4096);
        a[5] = *(const bf16x8*)(bufp + offA + 5120);
        a[6] = *(const bf16x8*)(bufp + offA + 6144);
        a[7] = *(const bf16x8*)(bufp + offA + 7168);
        if (kt + 3 < Kt) STAGE_H1(kt + 3);
        __builtin_amdgcn_sched_barrier(0);
        __builtin_amdgcn_s_barrier();
        asm volatile("s_waitcnt lgkmcnt(0)" ::: "memory");
        __builtin_amdgcn_sched_barrier(0);
        __builtin_amdgcn_s_setprio(1);
#pragma unroll
        for (int m = 4; m < 8; m++)
#pragma unroll
            for (int n = 0; n < 4; n++)
                acc[m][n] = __builtin_amdgcn_mfma_f32_16x16x32_bf16(a[m], b[n], acc[m][n], 0, 0, 0);
        __builtin_amdgcn_s_setprio(0);
        __builtin_amdgcn_sched_barrier(0);
    }
#undef STAGE_H0
#undef STAGE_H1

    // epilogue: frag row = (l>>4)*4 + r, col = l&15; n INNERMOST so the four
    // 32B store groups filling one 128B line issue back-to-back (full-sector merge).
    const int row0 = by * 256 + wr * 128 + ((l >> 4) << 2);
    const int col0 = bx * 256 + wc * 64 + (l & 15);
    const int seg = bx >> 1;  // EPI4: 512-col segment (256-tile never straddles)
    const size_t segoff = (size_t)seg * M * 512;
    const int c511 = col0 & 511;
    float bv[4];
#pragma unroll
    for (int n = 0; n < 4; n++) bv[n] = bias[col0 + n * 16];
#pragma unroll
    for (int m = 0; m < 8; m++) {
#pragma unroll
        for (int r = 0; r < 4; r++) {
            const int row = row0 + m * 16 + r;
            const size_t base = (size_t)row * N + col0;
#pragma unroll
            for (int n = 0; n < 4; n++) {
                float vv = acc[m][n][r] + bv[n];
                if constexpr (EPI == 2) {
                    vv = vv > 0.f ? vv : 0.f;
                    out16[base + n * 16] = f2bf(vv);
                } else if constexpr (EPI == 3) {
                    vv += bf2f(res16[base + n * 16]);
                    out16[base + n * 16] = f2bf(vv);
                } else if constexpr (EPI == 4) {
                    if (seg < 2) vv = vv > 0.f ? vv + 1.f : __expf(vv);
                    out16[segoff + (size_t)row * 512 + c511 + n * 16] = f2bf(vv);
                } else {
                    out16[base + n * 16] = f2bf(vv);
                }
            }
        }
    }
}

// ---------------- kv partial reduction ----------------
__global__ __launch_bounds__(256) void kv_partial(
    const ushort* __restrict__ km, const ushort* __restrict__ v,
    float* __restrict__ kvp, float* __restrict__ ksump, int S) {
    __shared__ ushort kms[32 * 64];
    __shared__ ushort vs[32 * 64];
    const int t = threadIdx.x;
    const int bh = blockIdx.y, b = bh >> 3, h = bh & 7;
    const int d0 = (t >> 4) * 4, e0 = (t & 15) * 4;
    float acc[4][4] = {};
    float ks = 0.f;
    const int s_base = blockIdx.x * 512;
    const int r = t >> 3, c8 = (t & 7) * 8;
    for (int s0 = 0; s0 < 512; s0 += 32) {
        size_t grow = ((size_t)b * S + s_base + s0 + r) * 512 + h * 64 + c8;
        *(uint4*)&kms[r * 64 + c8] = *(const uint4*)&km[grow];
        *(uint4*)&vs[r * 64 + c8] = *(const uint4*)&v[grow];
        __syncthreads();
#pragma unroll 4
        for (int s = 0; s < 32; ++s) {
            ushort4 ka = *(const ushort4*)&kms[s * 64 + d0];
            ushort4 vb = *(const ushort4*)&vs[s * 64 + e0];
            float a0 = bf2f(ka.x), a1 = bf2f(ka.y), a2 = bf2f(ka.z), a3 = bf2f(ka.w);
            float b0 = bf2f(vb.x), b1 = bf2f(vb.y), b2 = bf2f(vb.z), b3 = bf2f(vb.w);
            acc[0][0] += a0 * b0; acc[0][1] += a0 * b1; acc[0][2] += a0 * b2; acc[0][3] += a0 * b3;
            acc[1][0] += a1 * b0; acc[1][1] += a1 * b1; acc[1][2] += a1 * b2; acc[1][3] += a1 * b3;
            acc[2][0] += a2 * b0; acc[2][1] += a2 * b1; acc[2][2] += a2 * b2; acc[2][3] += a2 * b3;
            acc[3][0] += a3 * b0; acc[3][1] += a3 * b1; acc[3][2] += a3 * b2; acc[3][3] += a3 * b3;
            if (t < 64) ks += bf2f(kms[s * 64 + t]);
        }
        __syncthreads();
    }
    float* dst = kvp + ((size_t)bh * 16 + blockIdx.x) * 4096;
#pragma unroll
    for (int i = 0; i < 4; i++)
#pragma unroll
        for (int j = 0; j < 4; j++)
            dst[(d0 + i) * 64 + e0 + j] = acc[i][j];
    if (t < 64) ksump[((size_t)bh * 16 + blockIdx.x) * 64 + t] = ks;
}

// reduce partials; kv emitted TRANSPOSED per head as bf16: kvt[bh][e][d]
__global__ void kv_reduce(const float* __restrict__ kvp, const float* __restrict__ ksump,
                          ushort* __restrict__ kvt, float* __restrict__ ksum) {
    int i = blockIdx.x * 256 + threadIdx.x;
    if (i < 32 * 4096) {
        int bh = i >> 12, de = i & 4095;
        int d = de >> 6, e = de & 63;
        float s = 0.f;
#pragma unroll
        for (int c = 0; c < 16; ++c) s += kvp[((size_t)bh * 16 + c) * 4096 + de];
        kvt[(size_t)bh * 4096 + e * 64 + d] = f2bf(s);
    } else {
        int j = i - 32 * 4096;
        if (j < 32 * 64) {
            int bh = j >> 6, d = j & 63;
            float s = 0.f;
#pragma unroll
            for (int c = 0; c < 16; ++c) s += ksump[((size_t)bh * 16 + c) * 64 + d];
            ksum[j] = s;
        }
    }
}

// ---------------- attn via MFMA: per (b,h) attn = qm[S,64] @ kv[64,64], * z ----------------
__global__ __launch_bounds__(256) void attn_mfma(
    const ushort* __restrict__ qm, const ushort* __restrict__ kvt,
    const float* __restrict__ ksum, ushort* __restrict__ attnE, int S) {
    __shared__ ushort As[128 * 128];
    __shared__ ushort Bs[128 * 64];
    __shared__ float zbuf[128][2];
    __shared__ float ks2[128];
    const int t = threadIdx.x, w = t >> 6, l = t & 63;
    const int cx = blockIdx.x, by = blockIdx.y;
    const int b = (by * 128) / S;
    const int h0 = cx * 2;
    const size_t arow0 = (size_t)(by * 128) * 512 + cx * 128;

#pragma unroll
    for (int rd = 0; rd < 8; ++rd) {
        const ushort* g = qm + arow0 + (size_t)(rd * 16 + w * 4 + (l >> 4)) * 512 + (l & 15) * 8;
        gload16(g, (char*)As + rd * 4096 + w * 1024);
    }
    const ushort* kvbase = kvt + (size_t)(b * 8 + h0) * 4096;
#pragma unroll
    for (int rd = 0; rd < 4; ++rd) {
        const ushort* g = kvbase + (rd * 32 + w * 8 + (l >> 3)) * 64 + (l & 7) * 8;
        gload16(g, (char*)Bs + rd * 4096 + w * 1024);
    }
    if (t < 128) ks2[t] = ksum[(b * 8 + h0) * 64 + t];
    __syncthreads();

    {
        const int r = t >> 1, hh = t & 1;
        float den = 0.f;
#pragma unroll
        for (int d0 = 0; d0 < 64; d0 += 8) {
            bf16x8 qv = *(const bf16x8*)&As[r * 128 + hh * 64 + d0];
#pragma unroll
            for (int j = 0; j < 8; j++) den += bf2f((ushort)qv[j]) * ks2[hh * 64 + d0 + j];
        }
        zbuf[r][hh] = 1.0f / (den + 1e-6f);
    }

    const int wr = w >> 1, wc = w & 1;
    const int ar = wr * 64 + (l & 15);
    const int br = wc * 64 + (l & 15);
    const int ko = (l >> 4) * 8;
    f32x4 acc[4][4] = {};
#pragma unroll
    for (int ks_ = 0; ks_ < 2; ++ks_) {
        bf16x8 a[4], bb[4];
#pragma unroll
        for (int m = 0; m < 4; m++)
            a[m] = *(const bf16x8*)&As[(ar + m * 16) * 128 + wc * 64 + ks_ * 32 + ko];
#pragma unroll
        for (int n = 0; n < 4; n++)
            bb[n] = *(const bf16x8*)&Bs[(br + n * 16) * 64 + ks_ * 32 + ko];
#pragma unroll
        for (int m = 0; m < 4; m++)
#pragma unroll
            for (int n = 0; n < 4; n++)
                acc[m][n] = __builtin_amdgcn_mfma_f32_16x16x32_bf16(a[m], bb[n], acc[m][n], 0, 0, 0);
    }
    __syncthreads();

    const int row0l = wr * 64 + ((l >> 4) << 2);
    ushort* outbase = attnE + (size_t)(by * 128) * 512 + cx * 128;
#pragma unroll
    for (int n = 0; n < 4; n++) {
#pragma unroll
        for (int m = 0; m < 4; m++) {
#pragma unroll
            for (int r = 0; r < 4; r++) {
                int rl = row0l + m * 16 + r;
                float z = zbuf[rl][wc];
                outbase[(size_t)rl * 512 + wc * 64 + n * 16 + (l & 15)] = f2bf(acc[m][n][r] * z);
            }
        }
    }
}

// ---------------- LayerNorm over bf16 input ----------------
template <int OUT32>
__global__ __launch_bounds__(256) void ln_bf16(
    const ushort* __restrict__ in, const float* __restrict__ g, const float* __restrict__ be,
    void* __restrict__ outp, int Mrows) {
    const int w = threadIdx.x >> 6, l = threadIdx.x & 63;
    const int row = blockIdx.x * 4 + w;
    if (row >= Mrows) return;
    const ushort* rp = in + (size_t)row * 512;
    uint4 u = *(const uint4*)&rp[l * 8];
    float x[8];
    x[0] = bf2f((ushort)(u.x & 0xffff)); x[1] = bf2f((ushort)(u.x >> 16));
    x[2] = bf2f((ushort)(u.y & 0xffff)); x[3] = bf2f((ushort)(u.y >> 16));
    x[4] = bf2f((ushort)(u.z & 0xffff)); x[5] = bf2f((ushort)(u.z >> 16));
    x[6] = bf2f((ushort)(u.w & 0xffff)); x[7] = bf2f((ushort)(u.w >> 16));
    float s = 0.f, ss = 0.f;
#pragma unroll
    for (int j = 0; j < 8; j++) { s += x[j]; ss += x[j] * x[j]; }
#pragma unroll
    for (int o = 1; o < 64; o <<= 1) {
        s += __shfl_xor(s, o, 64);
        ss += __shfl_xor(ss, o, 64);
    }
    float mean = s * (1.f / 512.f);
    float var = ss * (1.f / 512.f) - mean * mean;
    float rstd = rsqrtf(var + 1e-5f);
    float4 g0 = *(const float4*)&g[l * 8], g1v = *(const float4*)&g[l * 8 + 4];
    float4 b0 = *(const float4*)&be[l * 8], b1v = *(const float4*)&be[l * 8 + 4];
    float o0[8];
    o0[0] = (x[0] - mean) * rstd * g0.x + b0.x;
    o0[1] = (x[1] - mean) * rstd * g0.y + b0.y;
    o0[2] = (x[2] - mean) * rstd * g0.z + b0.z;
    o0[3] = (x[3] - mean) * rstd * g0.w + b0.w;
    o0[4] = (x[4] - mean) * rstd * g1v.x + b1v.x;
    o0[5] = (x[5] - mean) * rstd * g1v.y + b1v.y;
    o0[6] = (x[6] - mean) * rstd * g1v.z + b1v.z;
    o0[7] = (x[7] - mean) * rstd * g1v.w + b1v.w;
    if constexpr (OUT32) {
        float* op = (float*)outp + (size_t)row * 512;
        *(float4*)&op[l * 8] = make_float4(o0[0], o0[1], o0[2], o0[3]);
        *(float4*)&op[l * 8 + 4] = make_float4(o0[4], o0[5], o0[6], o0[7]);
    } else {
        ushort* op = (ushort*)outp + (size_t)row * 512;
        ushort4 u0, u1;
        u0.x = f2bf(o0[0]); u0.y = f2bf(o0[1]); u0.z = f2bf(o0[2]); u0.w = f2bf(o0[3]);
        u1.x = f2bf(o0[4]); u1.y = f2bf(o0[5]); u1.z = f2bf(o0[6]); u1.w = f2bf(o0[7]);
        *(ushort4*)&op[l * 8] = u0;
        *(ushort4*)&op[l * 8 + 4] = u1;
    }
}

extern "C" void kernel_launch(void* const* d_in, const int* in_sizes, int n_in,
                              void* d_out, int out_size, void* d_ws, size_t ws_size,
                              hipStream_t stream) {
    const int B = 4, S = 8192, E = 512, F = 2048;
    const int M = B * S;  // 32768
    const size_t SZ = (size_t)M * E * 2;  // 32 MiB
    const int SMEM = 131072;

    const float* src = (const float*)d_in[0];
    const float* Wq = (const float*)d_in[1];  const float* bq = (const float*)d_in[2];
    const float* Wk = (const float*)d_in[3];  const float* bk = (const float*)d_in[4];
    const float* Wv = (const float*)d_in[5];  const float* bv = (const float*)d_in[6];
    const float* Wo = (const float*)d_in[7];  const float* bo = (const float*)d_in[8];
    const float* W1 = (const float*)d_in[9];  const float* b1 = (const float*)d_in[10];
    const float* W2 = (const float*)d_in[11]; const float* b2 = (const float*)d_in[12];
    const float* g1 = (const float*)d_in[13]; const float* be1 = (const float*)d_in[14];
    const float* g2 = (const float*)d_in[15]; const float* be2 = (const float*)d_in[16];

    char* ws = (char*)d_ws;
    ushort* qm    = (ushort*)(ws + 0 * SZ);
    ushort* km    = (ushort*)(ws + 1 * SZ);
    ushort* v     = (ushort*)(ws + 2 * SZ);
    ushort* src16 = (ushort*)(ws + 3 * SZ);
    ushort* x16   = (ushort*)(ws + 4 * SZ);
    ushort* z16   = (ushort*)(ws + 5 * SZ);
    char*   tail  = ws + 6 * SZ;
    float*  kvp   = (float*)(tail);
    float*  ksump = (float*)(tail + 8388608);
    ushort* kvt   = (ushort*)(tail + 8519680);
    float*  ksum  = (float*)(tail + 8781824);
    float*  bqkv  = (float*)(tail + 8790016);
    ushort* wqkv  = (ushort*)(tail + 8796160);
    ushort* wot   = (ushort*)(tail + 10369024);
    ushort* w1t   = (ushort*)(tail + 10893312);
    ushort* w2t   = (ushort*)(tail + 12990464);
    ushort* attnE = km;
    ushort* y16   = v;
    ushort* hbuf  = (ushort*)(ws + 0);

    // allow 128 KB dynamic LDS on the GEMM instantiations (idempotent)
    hipFuncSetAttribute((const void*)gemm256<2>, hipFuncAttributeMaxDynamicSharedMemorySize, SMEM);
    hipFuncSetAttribute((const void*)gemm256<3>, hipFuncAttributeMaxDynamicSharedMemorySize, SMEM);
    hipFuncSetAttribute((const void*)gemm256<4>, hipFuncAttributeMaxDynamicSharedMemorySize, SMEM);

    // 1) converts
    conv_bf16<<<dim3((M * E / 4 + 255) / 256), 256, 0, stream>>>(src, src16, M * E / 4);
    wconv_t<<<dim3(E / 32, E / 32), 256, 0, stream>>>(Wq, wqkv, E, E);
    wconv_t<<<dim3(E / 32, E / 32), 256, 0, stream>>>(Wk, wqkv + 512 * 512, E, E);
    wconv_t<<<dim3(E / 32, E / 32), 256, 0, stream>>>(Wv, wqkv + 1024 * 512, E, E);
    wconv_t<<<dim3(E / 32, E / 32), 256, 0, stream>>>(Wo, wot, E, E);
    wconv_t<<<dim3(F / 32, E / 32), 256, 0, stream>>>(W1, w1t, E, F);
    wconv_t<<<dim3(E / 32, F / 32), 256, 0, stream>>>(W2, w2t, F, E);
    biascat<<<dim3(6), 256, 0, stream>>>(bq, bk, bv, bqkv);

    // 2) fused QKV GEMM (N=1536; elu+1 on q,k segments)
    gemm256<4><<<dim3(6 * 128), 512, SMEM, stream>>>(src16, wqkv, bqkv, nullptr, qm, M, 1536, E, 6);

    // 3) kv / ksum reduction
    kv_partial<<<dim3(16, 32), 256, 0, stream>>>(km, v, kvp, ksump, S);
    kv_reduce<<<dim3((32 * 4096 + 32 * 64 + 255) / 256), 256, 0, stream>>>(kvp, ksump, kvt, ksum);

    // 4) attention combine (MFMA)
    attn_mfma<<<dim3(4, M / 128), 256, 0, stream>>>(qm, kvt, ksum, attnE, S);

    // 5) output proj + bf16 residual, then LN -> x16
    gemm256<3><<<dim3(2 * 128), 512, SMEM, stream>>>(attnE, wot, bo, src16, y16, M, E, E, 2);
    ln_bf16<0><<<dim3(M / 4), 256, 0, stream>>>(y16, g1, be1, x16, M);

    // 6) FFN
    gemm256<2><<<dim3(8 * 128), 512, SMEM, stream>>>(x16, w1t, b1, nullptr, hbuf, M, F, E, 8);
    gemm256<3><<<dim3(2 * 128), 512, SMEM, stream>>>(hbuf, w2t, b2, x16, z16, M, E, F, 2);
    ln_bf16<1><<<dim3(M / 4), 256, 0, stream>>>(z16, g2, be2, (float*)d_out, M);
}